// Round 4
// baseline (519.996 us; speedup 1.0000x reference)
//
#include <hip/hip_runtime.h>

#define M_DIM 4096
#define K_DIM 4096
#define N_DIM 11008
#define BM 256
#define BN 256
#define BK 64            // bytes of K per tile iteration (int8)
#define NTILES (K_DIM / BK)   // 64

typedef int v4i  __attribute__((ext_vector_type(4)));
typedef int v16i __attribute__((ext_vector_type(16)));

// s_waitcnt immediates (gfx9 encoding: vmcnt[3:0]@0, exp[6:4], lgkm[13:8], vmcnt[5:4]@[15:14])
#define WAIT_VM8 0x3F78   // vmcnt<=8
#define WAIT_VM0 0x3F70   // vmcnt<=0

__device__ __forceinline__ void load_lds16(const void* g, void* l) {
    __builtin_amdgcn_global_load_lds(
        (const __attribute__((address_space(1))) void*)g,
        (__attribute__((address_space(3))) void*)l,
        16, 0, 0);
}

__global__ void pack_x_kernel(const int* __restrict__ x, signed char* __restrict__ out,
                              const int* __restrict__ zp_p, int n4) {
    int i = blockIdx.x * blockDim.x + threadIdx.x;
    if (i >= n4) return;
    int zp = zp_p[0];
    int4 v = ((const int4*)x)[i];
    unsigned int p = ((unsigned int)(v.x - zp) & 0xFF)
                   | (((unsigned int)(v.y - zp) & 0xFF) << 8)
                   | (((unsigned int)(v.z - zp) & 0xFF) << 16)
                   | (((unsigned int)(v.w - zp) & 0xFF) << 24);
    ((unsigned int*)out)[i] = p;
}

__global__ void pack_w_kernel(const int* __restrict__ w, signed char* __restrict__ out, int n4) {
    int i = blockIdx.x * blockDim.x + threadIdx.x;
    if (i >= n4) return;
    int4 v = ((const int4*)w)[i];
    unsigned int p = ((unsigned int)v.x & 0xFF)
                   | (((unsigned int)v.y & 0xFF) << 8)
                   | (((unsigned int)v.z & 0xFF) << 16)
                   | (((unsigned int)v.w & 0xFF) << 24);
    ((unsigned int*)out)[i] = p;
}

// LDS tile layout (per buffer): 256 rows x 4 granules of 16B (row = 64B = BK).
// Granule g of row r stored at slot r*4 + (g ^ ((r>>1)&3)) -> per-8-lane bank-quad
// permutation on both staging writes and fragment reads.
__global__ __launch_bounds__(256, 1) void gemm_i8_kernel(
    const signed char* __restrict__ A8,   // [M][K] int8 (x - zp)
    const signed char* __restrict__ B8,   // [N][K] int8 (w)
    const float* __restrict__ bias,
    const float* __restrict__ xs_p, const float* __restrict__ ws_p,
    const float* __restrict__ os_p, const int* __restrict__ ozp_p,
    int* __restrict__ out) {
    __shared__ v4i As0[BM * BK / 16];   // 1024 slots = 16 KB
    __shared__ v4i Bs0[BN * BK / 16];
    __shared__ v4i As1[BM * BK / 16];
    __shared__ v4i Bs1[BN * BK / 16];   // total 64 KB

    const int tid  = threadIdx.x;
    const int lane = tid & 63;
    const int wave = tid >> 6;

    // ---- XCD-aware block swizzle: 16 m-blocks -> 2 per XCD, m fastest ----
    const int bid   = blockIdx.x;
    const int xcd   = bid & 7;
    const int local = bid >> 3;            // [0, 86)
    const int m_blk = xcd * 2 + (local & 1);
    const int n_blk = local >> 1;          // [0, 43)
    const int m0 = m_blk * BM;
    const int n0 = n_blk * BN;

    // ---- staging: 8 granules per thread per tile (4 A + 4 B) ----
    int offA[4], offB[4], ldsSlot[4];
#pragma unroll
    for (int j = 0; j < 4; ++j) {
        const int s   = tid + 256 * j;     // slot in [0, 1024)
        const int row = s >> 2;
        const int gg  = (s & 3) ^ ((row >> 1) & 3);
        offA[j]    = (m0 + row) * K_DIM + gg * 16;
        offB[j]    = (n0 + row) * K_DIM + gg * 16;
        ldsSlot[j] = s;
    }

    // ---- fragment slots: wave-tile 128x128, 4x4 of 32x32x32 ----
    const int waveM = wave >> 1, waveN = wave & 1;
    const int l31 = lane & 31, h = lane >> 5;
    int aSlot[4][2], bSlot[4][2];
#pragma unroll
    for (int t = 0; t < 4; ++t) {
        const int rA = waveM * 128 + t * 32 + l31;
        const int rB = waveN * 128 + t * 32 + l31;
#pragma unroll
        for (int s = 0; s < 2; ++s) {
            const int g = 2 * s + h;
            aSlot[t][s] = rA * 4 + (g ^ ((rA >> 1) & 3));
            bSlot[t][s] = rB * 4 + (g ^ ((rB >> 1) & 3));
        }
    }

    v16i acc[4][4];
#pragma unroll
    for (int mt = 0; mt < 4; ++mt)
#pragma unroll
        for (int nt = 0; nt < 4; ++nt)
#pragma unroll
            for (int r = 0; r < 16; ++r) acc[mt][nt][r] = 0;

    auto stage = [&](int tile, v4i* Asb, v4i* Bsb) {
        const int koff = tile * BK;
#pragma unroll
        for (int j = 0; j < 4; ++j) load_lds16(A8 + offA[j] + koff, (char*)(Asb + ldsSlot[j]));
#pragma unroll
        for (int j = 0; j < 4; ++j) load_lds16(B8 + offB[j] + koff, (char*)(Bsb + ldsSlot[j]));
    };
    auto compute = [&](const v4i* Asb, const v4i* Bsb) {
#pragma unroll
        for (int s = 0; s < 2; ++s) {
            v4i a[4], b[4];
#pragma unroll
            for (int t = 0; t < 4; ++t) a[t] = Asb[aSlot[t][s]];
#pragma unroll
            for (int t = 0; t < 4; ++t) b[t] = Bsb[bSlot[t][s]];
#pragma unroll
            for (int mt = 0; mt < 4; ++mt)
#pragma unroll
                for (int nt = 0; nt < 4; ++nt)
                    acc[mt][nt] = __builtin_amdgcn_mfma_i32_32x32x32_i8(
                        a[mt], b[nt], acc[mt][nt], 0, 0, 0);
        }
    };

    // ---- async double-buffered pipeline over 64 K-tiles ----
    stage(0, As0, Bs0);          // 8 in flight
    stage(1, As1, Bs1);          // 16 in flight

#pragma unroll 1
    for (int kk = 0; kk < NTILES / 2 - 1; ++kk) {   // 31 iters
        const int k = 2 * kk;
        __builtin_amdgcn_s_waitcnt(WAIT_VM8);   // tile k landed; k+1 flying
        __builtin_amdgcn_s_barrier();
        compute(As0, Bs0);
        __builtin_amdgcn_s_barrier();           // all reads of buf0 done
        stage(k + 2, As0, Bs0);                 // 16 in flight
        __builtin_amdgcn_s_waitcnt(WAIT_VM8);   // tile k+1 landed; k+2 flying
        __builtin_amdgcn_s_barrier();
        compute(As1, Bs1);
        __builtin_amdgcn_s_barrier();
        stage(k + 3, As1, Bs1);                 // 16 in flight
    }
    // tail: tiles 62, 63
    __builtin_amdgcn_s_waitcnt(WAIT_VM8);
    __builtin_amdgcn_s_barrier();
    compute(As0, Bs0);
    __builtin_amdgcn_s_waitcnt(WAIT_VM0);
    __builtin_amdgcn_s_barrier();
    compute(As1, Bs1);

    // ---- epilogue: dequant + bias, requant to [0,255] ----
    // C/D 32x32: col = lane&31, row = (r&3) + 8*(r>>2) + 4*(lane>>5)
    const float scale  = xs_p[0] * ws_p[0];
    const float inv_os = 1.0f / os_p[0];
    const int   ozp    = ozp_p[0];
#pragma unroll
    for (int mt = 0; mt < 4; ++mt) {
        const int rbase = m0 + waveM * 128 + mt * 32 + 4 * h;
#pragma unroll
        for (int nt = 0; nt < 4; ++nt) {
            const int col = n0 + waveN * 128 + nt * 32 + l31;
            const float bv = bias[col];
#pragma unroll
            for (int r = 0; r < 16; ++r) {
                const int row = rbase + (r & 3) + 8 * (r >> 2);
                float y = (float)acc[mt][nt][r] * scale + bv;
                int q = (int)rintf(y * inv_os) + ozp;
                q = q < 0 ? 0 : (q > 255 ? 255 : q);
                out[(long)row * N_DIM + col] = q;
            }
        }
    }
}

extern "C" void kernel_launch(void* const* d_in, const int* in_sizes, int n_in,
                              void* d_out, int out_size, void* d_ws, size_t ws_size,
                              hipStream_t stream) {
    const int*   x_q  = (const int*)d_in[0];
    const int*   w_q  = (const int*)d_in[1];
    const float* bias = (const float*)d_in[2];
    const float* xs   = (const float*)d_in[3];
    const float* wsc  = (const float*)d_in[4];
    const float* os   = (const float*)d_in[5];
    const int*   xzp  = (const int*)d_in[6];
    const int*   ozp  = (const int*)d_in[7];

    signed char* x8 = (signed char*)d_ws;                               // 16 MB
    signed char* w8 = (signed char*)d_ws + (size_t)M_DIM * K_DIM;       // 45 MB

    const int nx4 = M_DIM * K_DIM / 4;
    pack_x_kernel<<<(nx4 + 255) / 256, 256, 0, stream>>>(x_q, x8, xzp, nx4);
    const int nw4 = N_DIM * K_DIM / 4;
    pack_w_kernel<<<(nw4 + 255) / 256, 256, 0, stream>>>(w_q, w8, nw4);

    const int nblocks = (M_DIM / BM) * (N_DIM / BN);   // 16 * 43 = 688
    gemm_i8_kernel<<<nblocks, 256, 0, stream>>>(x8, w8, bias, xs, wsc, os, ozp, (int*)d_out);
}